// Round 1
// baseline (748.061 us; speedup 1.0000x reference)
//
#include <hip/hip_runtime.h>
#include <cstdint>
#include <cstddef>

// Problem constants (fixed by reference)
#define NN 100000          // nodes
#define EE 800000          // edges
#define HD 128             // hidden dim
#define OD 64              // output dim
#define NB_SCAN 391        // ceil(NN/256)
#define WPL 400000         // dropout mask words per layer = NN*HD/32
#define PARTITIONABLE_RNG 1  // modern JAX default; flip to 0 for legacy split-iota scheme

// ---------------- Threefry-2x32 (20 rounds), bit-exact vs JAX ----------------
__host__ __device__ __forceinline__ void tf2x32(unsigned k0, unsigned k1,
                                                unsigned x0, unsigned x1,
                                                unsigned& o0, unsigned& o1) {
  unsigned ks2 = k0 ^ k1 ^ 0x1BD11BDAu;
#define TFR(r) { x0 += x1; x1 = (x1 << (r)) | (x1 >> (32 - (r))); x1 ^= x0; }
  x0 += k0; x1 += k1;
  TFR(13) TFR(15) TFR(26) TFR(6)
  x0 += k1; x1 += ks2 + 1u;
  TFR(17) TFR(29) TFR(16) TFR(24)
  x0 += ks2; x1 += k0 + 2u;
  TFR(13) TFR(15) TFR(26) TFR(6)
  x0 += k0; x1 += k1 + 3u;
  TFR(17) TFR(29) TFR(16) TFR(24)
  x0 += k1; x1 += ks2 + 4u;
  TFR(13) TFR(15) TFR(26) TFR(6)
  x0 += ks2; x1 += k0 + 5u;
#undef TFR
  o0 = x0; o1 = x1;
}

// ---------------- CSR build ----------------
__global__ __launch_bounds__(256) void k_deg(const int* __restrict__ ei,
                                             int* __restrict__ deg) {
  int e = blockIdx.x * 256 + threadIdx.x;
  if (e >= EE) return;
  unsigned d = (unsigned)ei[EE + e];
  if (d >= NN) d = 0;  // safety clamp (dtype insurance)
  atomicAdd(&deg[d], 1);
}

__global__ __launch_bounds__(256) void k_scan_block(const int* __restrict__ deg,
                                                    int* __restrict__ rs,
                                                    int* __restrict__ bsum) {
  __shared__ int sh[256];
  int tid = threadIdx.x;
  int i = blockIdx.x * 256 + tid;
  int v = (i < NN) ? deg[i] : 0;
  sh[tid] = v;
  __syncthreads();
  for (int off = 1; off < 256; off <<= 1) {
    int add = (tid >= off) ? sh[tid - off] : 0;
    __syncthreads();
    sh[tid] += add;
    __syncthreads();
  }
  if (i < NN) rs[i] = sh[tid] - v;            // exclusive within block
  if (tid == 255) bsum[blockIdx.x] = sh[255]; // block total
}

__global__ __launch_bounds__(512) void k_scan_bsum(const int* __restrict__ bsum,
                                                   int* __restrict__ boff) {
  __shared__ int sh[512];
  int tid = threadIdx.x;
  int v = (tid < NB_SCAN) ? bsum[tid] : 0;
  sh[tid] = v;
  __syncthreads();
  for (int off = 1; off < 512; off <<= 1) {
    int add = (tid >= off) ? sh[tid - off] : 0;
    __syncthreads();
    sh[tid] += add;
    __syncthreads();
  }
  if (tid < NB_SCAN) boff[tid] = sh[tid] - v; // exclusive block offsets
}

__global__ __launch_bounds__(256) void k_scan_fix(int* __restrict__ rs,
                                                  const int* __restrict__ boff,
                                                  const int* __restrict__ deg,
                                                  float* __restrict__ invd,
                                                  int* __restrict__ fill) {
  int i = blockIdx.x * 256 + threadIdx.x;
  if (i < NN) {
    rs[i] += boff[i >> 8];
    int d = deg[i];
    invd[i] = (d > 0) ? 1.0f / (float)d : 0.0f;
    fill[i] = 0;
  }
  if (i == 0) rs[NN] = EE;
}

__global__ __launch_bounds__(256) void k_fill(const int* __restrict__ ei,
                                              const int* __restrict__ rs,
                                              int* __restrict__ fill,
                                              int* __restrict__ esrc) {
  int e = blockIdx.x * 256 + threadIdx.x;
  if (e >= EE) return;
  unsigned s = (unsigned)ei[e];
  unsigned d = (unsigned)ei[EE + e];
  if (s >= NN) s = 0;
  if (d >= NN) d = 0;
  int p = atomicAdd(&fill[d], 1);
  esrc[rs[d] + p] = (int)s;
}

// ---------------- Dropout mask precompute (bit-exact JAX) ----------------
__global__ __launch_bounds__(256) void k_masks(unsigned* __restrict__ masks,
                                               unsigned a0, unsigned a1,
                                               unsigned b0, unsigned b1,
                                               unsigned c0, unsigned c1) {
#if PARTITIONABLE_RNG
  // bits[i] = r0 ^ r1 of threefry(fkey, (0, i)); keep = MSB clear (u < 0.5)
  unsigned t = blockIdx.x * 256 + threadIdx.x;
  if (t >= 3u * WPL) return;
  unsigned l = t / WPL;
  unsigned w = t - l * WPL;
  unsigned k0 = (l == 0) ? a0 : ((l == 1) ? b0 : c0);
  unsigned k1 = (l == 0) ? a1 : ((l == 1) ? b1 : c1);
  unsigned bits = 0u;
#pragma unroll 4
  for (int b = 0; b < 32; ++b) {
    unsigned i = w * 32u + (unsigned)b;
    unsigned r0, r1;
    tf2x32(k0, k1, 0u, i, r0, r1);
    bits |= ((~(r0 ^ r1)) >> 31) << b;
  }
  masks[t] = bits;
#else
  // legacy split-iota: element i<half <- x0 of (i, i+half); i>=half <- x1
  const unsigned HALF = (NN * HD) / 2;   // 6,400,000
  const unsigned WPH = HALF / 32;        // 200,000
  unsigned t = blockIdx.x * 256 + threadIdx.x;
  if (t >= 3u * WPH) return;
  unsigned l = t / WPH;
  unsigned w = t - l * WPH;
  unsigned k0 = (l == 0) ? a0 : ((l == 1) ? b0 : c0);
  unsigned k1 = (l == 0) ? a1 : ((l == 1) ? b1 : c1);
  unsigned w0 = 0u, w1 = 0u;
#pragma unroll 4
  for (int b = 0; b < 32; ++b) {
    unsigned i = w * 32u + (unsigned)b;
    unsigned r0, r1;
    tf2x32(k0, k1, i, i + HALF, r0, r1);
    w0 |= ((~r0) >> 31) << b;
    w1 |= ((~r1) >> 31) << b;
  }
  masks[l * WPL + w] = w0;
  masks[l * WPL + WPH + w] = w1;
#endif
}

// ---------------- Mean aggregation (CSR gather-sum) ----------------
__global__ __launch_bounds__(256) void k_agg(const float* __restrict__ x,
                                             const int* __restrict__ esrc,
                                             const int* __restrict__ rs,
                                             const float* __restrict__ invd,
                                             float* __restrict__ agg) {
  int wid = (blockIdx.x * 256 + threadIdx.x) >> 6;  // wave id = node
  int lane = threadIdx.x & 63;
  if (wid >= NN) return;
  int s = rs[wid], e = rs[wid + 1];
  const float2* xb = (const float2*)x;
  float ax = 0.0f, ay = 0.0f;
  for (int i = s; i < e; ++i) {
    int src = esrc[i];
    float2 v = xb[(size_t)src * 64 + lane];
    ax += v.x; ay += v.y;
  }
  float dsc = invd[wid];
  float2 o; o.x = ax * dsc; o.y = ay * dsc;
  ((float2*)agg)[(size_t)wid * 64 + lane] = o;
}

// ---------------- Layer GEMM: out = dropout(leakyrelu(agg@Wl^T + x@Wr^T + b)) ----------------
__global__ __launch_bounds__(256) void k_layer(const float* __restrict__ xin,
                                               const float* __restrict__ agg,
                                               const float* __restrict__ Wl,
                                               const float* __restrict__ Wr,
                                               const float* __restrict__ bias,
                                               const unsigned* __restrict__ mask,
                                               float* __restrict__ xout) {
  __shared__ float As[32][132];  // A chunk, transposed [k][node], padded
  __shared__ float Ws[32][132];  // W chunk, transposed [k][out], padded
  const int tid = threadIdx.x;
  const int tx = tid & 15;       // output group: j0 = tx*8
  const int ty = tid >> 4;       // node group:   n0 = ty*8
  const int nbase = blockIdx.x * 128;

  float acc[8][8];
#pragma unroll
  for (int i = 0; i < 8; ++i)
#pragma unroll
    for (int j = 0; j < 8; ++j) acc[i][j] = 0.0f;

  const int r = tid >> 1;         // 0..127 (A row within tile AND W row)
  const int h = (tid & 1) << 4;   // 0 / 16 (k half within 32-chunk)
  const int gn = nbase + r;
  const bool rowOk = (gn < NN);

#pragma unroll 1
  for (int s = 0; s < 2; ++s) {
    const float* __restrict__ A = s ? xin : agg;
    const float* __restrict__ W = s ? Wr : Wl;
#pragma unroll 1
    for (int k0 = 0; k0 < 128; k0 += 32) {
      float4 av0 = make_float4(0, 0, 0, 0), av1 = av0, av2 = av0, av3 = av0;
      if (rowOk) {
        const float* ap = A + (size_t)gn * 128 + k0 + h;
        av0 = *(const float4*)(ap + 0);
        av1 = *(const float4*)(ap + 4);
        av2 = *(const float4*)(ap + 8);
        av3 = *(const float4*)(ap + 12);
      }
      const float* wp = W + r * 128 + k0 + h;
      float4 wv0 = *(const float4*)(wp + 0);
      float4 wv1 = *(const float4*)(wp + 4);
      float4 wv2 = *(const float4*)(wp + 8);
      float4 wv3 = *(const float4*)(wp + 12);
      __syncthreads();
      As[h + 0][r] = av0.x;  As[h + 1][r] = av0.y;  As[h + 2][r] = av0.z;  As[h + 3][r] = av0.w;
      As[h + 4][r] = av1.x;  As[h + 5][r] = av1.y;  As[h + 6][r] = av1.z;  As[h + 7][r] = av1.w;
      As[h + 8][r] = av2.x;  As[h + 9][r] = av2.y;  As[h + 10][r] = av2.z; As[h + 11][r] = av2.w;
      As[h + 12][r] = av3.x; As[h + 13][r] = av3.y; As[h + 14][r] = av3.z; As[h + 15][r] = av3.w;
      Ws[h + 0][r] = wv0.x;  Ws[h + 1][r] = wv0.y;  Ws[h + 2][r] = wv0.z;  Ws[h + 3][r] = wv0.w;
      Ws[h + 4][r] = wv1.x;  Ws[h + 5][r] = wv1.y;  Ws[h + 6][r] = wv1.z;  Ws[h + 7][r] = wv1.w;
      Ws[h + 8][r] = wv2.x;  Ws[h + 9][r] = wv2.y;  Ws[h + 10][r] = wv2.z; Ws[h + 11][r] = wv2.w;
      Ws[h + 12][r] = wv3.x; Ws[h + 13][r] = wv3.y; Ws[h + 14][r] = wv3.z; Ws[h + 15][r] = wv3.w;
      __syncthreads();
#pragma unroll 8
      for (int kk = 0; kk < 32; ++kk) {
        const float4 a0 = *(const float4*)&As[kk][ty * 8];
        const float4 a1 = *(const float4*)&As[kk][ty * 8 + 4];
        const float4 w0 = *(const float4*)&Ws[kk][tx * 8];
        const float4 w1 = *(const float4*)&Ws[kk][tx * 8 + 4];
        const float af[8] = {a0.x, a0.y, a0.z, a0.w, a1.x, a1.y, a1.z, a1.w};
        const float wf[8] = {w0.x, w0.y, w0.z, w0.w, w1.x, w1.y, w1.z, w1.w};
#pragma unroll
        for (int i = 0; i < 8; ++i)
#pragma unroll
          for (int j = 0; j < 8; ++j)
            acc[i][j] = fmaf(af[i], wf[j], acc[i][j]);
      }
    }
  }

  const int j0 = tx << 3;
  float bf[8];
#pragma unroll
  for (int j = 0; j < 8; ++j) bf[j] = bias[j0 + j];
#pragma unroll
  for (int i = 0; i < 8; ++i) {
    const int n = nbase + ty * 8 + i;
    if (n >= NN) continue;
    const unsigned flat0 = (unsigned)n * 128u + (unsigned)j0;
    const unsigned mw = mask[flat0 >> 5];
    float o[8];
#pragma unroll
    for (int j = 0; j < 8; ++j) {
      float v = acc[i][j] + bf[j];
      v = (v > 0.0f) ? v : 0.01f * v;                       // leaky_relu(0.01)
      o[j] = ((mw >> ((flat0 + (unsigned)j) & 31u)) & 1u) ? (v + v) : 0.0f;  // dropout p=0.5
    }
    float4* op = (float4*)(xout + (size_t)n * 128 + j0);
    op[0] = make_float4(o[0], o[1], o[2], o[3]);
    op[1] = make_float4(o[4], o[5], o[6], o[7]);
  }
}

// ---------------- Final projection: out = x @ Wo^T + bo ----------------
__global__ __launch_bounds__(256) void k_final(const float* __restrict__ xin,
                                               const float* __restrict__ Wo,
                                               const float* __restrict__ bo,
                                               float* __restrict__ out) {
  __shared__ float As[32][132];
  __shared__ float Ws[32][72];
  const int tid = threadIdx.x;
  const int tx = tid & 7;     // j0 = tx*8 (64 outputs)
  const int ty = tid >> 3;    // 0..31, n0 = ty*4
  const int nbase = blockIdx.x * 128;

  float acc[4][8];
#pragma unroll
  for (int i = 0; i < 4; ++i)
#pragma unroll
    for (int j = 0; j < 8; ++j) acc[i][j] = 0.0f;

  const int r = tid >> 1;
  const int h = (tid & 1) << 4;
  const int gn = nbase + r;
  const bool rowOk = (gn < NN);
  const int wj = tid >> 2;          // 0..63
  const int wq = (tid & 3) << 3;    // 0,8,16,24

#pragma unroll 1
  for (int k0 = 0; k0 < 128; k0 += 32) {
    float4 av0 = make_float4(0, 0, 0, 0), av1 = av0, av2 = av0, av3 = av0;
    if (rowOk) {
      const float* ap = xin + (size_t)gn * 128 + k0 + h;
      av0 = *(const float4*)(ap + 0);
      av1 = *(const float4*)(ap + 4);
      av2 = *(const float4*)(ap + 8);
      av3 = *(const float4*)(ap + 12);
    }
    const float* wp = Wo + wj * 128 + k0 + wq;
    float4 wv0 = *(const float4*)(wp + 0);
    float4 wv1 = *(const float4*)(wp + 4);
    __syncthreads();
    As[h + 0][r] = av0.x;  As[h + 1][r] = av0.y;  As[h + 2][r] = av0.z;  As[h + 3][r] = av0.w;
    As[h + 4][r] = av1.x;  As[h + 5][r] = av1.y;  As[h + 6][r] = av1.z;  As[h + 7][r] = av1.w;
    As[h + 8][r] = av2.x;  As[h + 9][r] = av2.y;  As[h + 10][r] = av2.z; As[h + 11][r] = av2.w;
    As[h + 12][r] = av3.x; As[h + 13][r] = av3.y; As[h + 14][r] = av3.z; As[h + 15][r] = av3.w;
    Ws[wq + 0][wj] = wv0.x; Ws[wq + 1][wj] = wv0.y; Ws[wq + 2][wj] = wv0.z; Ws[wq + 3][wj] = wv0.w;
    Ws[wq + 4][wj] = wv1.x; Ws[wq + 5][wj] = wv1.y; Ws[wq + 6][wj] = wv1.z; Ws[wq + 7][wj] = wv1.w;
    __syncthreads();
#pragma unroll 8
    for (int kk = 0; kk < 32; ++kk) {
      const float4 a = *(const float4*)&As[kk][ty * 4];
      const float4 w0 = *(const float4*)&Ws[kk][tx * 8];
      const float4 w1 = *(const float4*)&Ws[kk][tx * 8 + 4];
      const float af[4] = {a.x, a.y, a.z, a.w};
      const float wf[8] = {w0.x, w0.y, w0.z, w0.w, w1.x, w1.y, w1.z, w1.w};
#pragma unroll
      for (int i = 0; i < 4; ++i)
#pragma unroll
        for (int j = 0; j < 8; ++j)
          acc[i][j] = fmaf(af[i], wf[j], acc[i][j]);
    }
  }

  const int j0 = tx << 3;
  float bf[8];
#pragma unroll
  for (int j = 0; j < 8; ++j) bf[j] = bo[j0 + j];
#pragma unroll
  for (int i = 0; i < 4; ++i) {
    const int n = nbase + ty * 4 + i;
    if (n >= NN) continue;
    float4* op = (float4*)(out + (size_t)n * 64 + j0);
    op[0] = make_float4(acc[i][0] + bf[0], acc[i][1] + bf[1], acc[i][2] + bf[2], acc[i][3] + bf[3]);
    op[1] = make_float4(acc[i][4] + bf[4], acc[i][5] + bf[5], acc[i][6] + bf[6], acc[i][7] + bf[7]);
  }
}

// ---------------- Host launch ----------------
extern "C" void kernel_launch(void* const* d_in, const int* in_sizes, int n_in,
                              void* d_out, int out_size, void* d_ws, size_t ws_size,
                              hipStream_t stream) {
  const float* x  = (const float*)d_in[0];
  const int*   ei = (const int*)d_in[1];      // [2][E]: row0 = src, row1 = dst
  const float* Wl = (const float*)d_in[2];    // [3][128][128]
  const float* Wr = (const float*)d_in[3];
  const float* b  = (const float*)d_in[4];    // [3][128]
  const float* Wo = (const float*)d_in[5];    // [64][128]
  const float* bo = (const float*)d_in[6];
  float* out = (float*)d_out;

  char* wsp = (char*)d_ws;
  size_t off = 0;
  auto take = [&](size_t bytes) -> void* {
    off = (off + 255) & ~(size_t)255;
    void* p = wsp + off;
    off += bytes;
    return p;
  };
  float*    bufA  = (float*)take((size_t)NN * 128 * 4);
  float*    bufB  = (float*)take((size_t)NN * 128 * 4);
  unsigned* masks = (unsigned*)take((size_t)3 * WPL * 4);
  int*      rs    = (int*)take((size_t)(NN + 1) * 4);
  int*      esrc  = (int*)take((size_t)EE * 4);
  int*      deg   = (int*)take((size_t)NN * 4);
  int*      fill  = (int*)take((size_t)NN * 4);
  float*    invd  = (float*)take((size_t)NN * 4);
  int*      bsum  = (int*)take(512 * 4);
  int*      boff  = (int*)take(512 * 4);

  // ---- CSR build ----
  hipMemsetAsync(deg, 0, (size_t)NN * 4, stream);
  k_deg<<<(EE + 255) / 256, 256, 0, stream>>>(ei, deg);
  k_scan_block<<<NB_SCAN, 256, 0, stream>>>(deg, rs, bsum);
  k_scan_bsum<<<1, 512, 0, stream>>>(bsum, boff);
  k_scan_fix<<<NB_SCAN, 256, 0, stream>>>(rs, boff, deg, invd, fill);
  k_fill<<<(EE + 255) / 256, 256, 0, stream>>>(ei, rs, fill, esrc);

  // ---- dropout masks (host-side threefry fold_in: key(42), fold l) ----
  unsigned fk[3][2];
  for (int l = 0; l < 3; ++l) tf2x32(0u, 42u, 0u, (unsigned)l, fk[l][0], fk[l][1]);
#if PARTITIONABLE_RNG
  int mthreads = 3 * WPL;
#else
  int mthreads = 3 * (WPL / 2);
#endif
  k_masks<<<(mthreads + 255) / 256, 256, 0, stream>>>(masks, fk[0][0], fk[0][1],
                                                      fk[1][0], fk[1][1], fk[2][0], fk[2][1]);

  // ---- layers (GEMM output aliases agg buffer: per-block row ranges are disjoint) ----
  const int gemmBlocks = (NN + 127) / 128;   // 782
  const int aggBlocks  = (NN + 3) / 4;       // 25000 (4 waves/block, wave per node)

  k_agg<<<aggBlocks, 256, 0, stream>>>(x, esrc, rs, invd, bufA);
  k_layer<<<gemmBlocks, 256, 0, stream>>>(x, bufA, Wl, Wr, b, masks, bufA);

  k_agg<<<aggBlocks, 256, 0, stream>>>(bufA, esrc, rs, invd, bufB);
  k_layer<<<gemmBlocks, 256, 0, stream>>>(bufA, bufB, Wl + 16384, Wr + 16384, b + 128,
                                          masks + WPL, bufB);

  k_agg<<<aggBlocks, 256, 0, stream>>>(bufB, esrc, rs, invd, bufA);
  k_layer<<<gemmBlocks, 256, 0, stream>>>(bufB, bufA, Wl + 32768, Wr + 32768, b + 256,
                                          masks + 2 * WPL, bufA);

  k_final<<<gemmBlocks, 256, 0, stream>>>(bufA, Wo, bo, out);

  (void)in_sizes; (void)n_in; (void)out_size; (void)ws_size;
}

// Round 2
// 519.461 us; speedup vs baseline: 1.4401x; 1.4401x over previous
//
#include <hip/hip_runtime.h>
#include <cstdint>
#include <cstddef>

// Problem constants (fixed by reference)
#define NN 100000          // nodes
#define EE 800000          // edges
#define HD 128             // hidden dim
#define OD 64              // output dim
#define NB_SCAN 391        // ceil(NN/256)
#define WPL 400000         // dropout mask words per layer = NN*HD/32

typedef __attribute__((ext_vector_type(8))) short s16x8;
typedef __attribute__((ext_vector_type(4))) float f32x4;
typedef __attribute__((ext_vector_type(8))) unsigned short u16x8;

// RNE float -> bf16 (no NaN concern in this workload)
__device__ __forceinline__ unsigned short f2bf(float f) {
  unsigned u = __float_as_uint(f);
  return (unsigned short)((u + 0x7FFFu + ((u >> 16) & 1u)) >> 16);
}
__device__ __forceinline__ float bf2f(unsigned short v) {
  return __uint_as_float(((unsigned)v) << 16);
}

// ---------------- Threefry-2x32 (20 rounds), bit-exact vs JAX ----------------
__host__ __device__ __forceinline__ void tf2x32(unsigned k0, unsigned k1,
                                                unsigned x0, unsigned x1,
                                                unsigned& o0, unsigned& o1) {
  unsigned ks2 = k0 ^ k1 ^ 0x1BD11BDAu;
#define TFR(r) { x0 += x1; x1 = (x1 << (r)) | (x1 >> (32 - (r))); x1 ^= x0; }
  x0 += k0; x1 += k1;
  TFR(13) TFR(15) TFR(26) TFR(6)
  x0 += k1; x1 += ks2 + 1u;
  TFR(17) TFR(29) TFR(16) TFR(24)
  x0 += ks2; x1 += k0 + 2u;
  TFR(13) TFR(15) TFR(26) TFR(6)
  x0 += k0; x1 += k1 + 3u;
  TFR(17) TFR(29) TFR(16) TFR(24)
  x0 += k1; x1 += ks2 + 4u;
  TFR(13) TFR(15) TFR(26) TFR(6)
  x0 += ks2; x1 += k0 + 5u;
#undef TFR
  o0 = x0; o1 = x1;
}

// ---------------- CSR build ----------------
__global__ __launch_bounds__(256) void k_deg(const int* __restrict__ ei,
                                             int* __restrict__ deg) {
  int e = blockIdx.x * 256 + threadIdx.x;
  if (e >= EE) return;
  unsigned d = (unsigned)ei[EE + e];
  if (d >= NN) d = 0;
  atomicAdd(&deg[d], 1);
}

__global__ __launch_bounds__(256) void k_scan_block(const int* __restrict__ deg,
                                                    int* __restrict__ rs,
                                                    int* __restrict__ bsum) {
  __shared__ int sh[256];
  int tid = threadIdx.x;
  int i = blockIdx.x * 256 + tid;
  int v = (i < NN) ? deg[i] : 0;
  sh[tid] = v;
  __syncthreads();
  for (int off = 1; off < 256; off <<= 1) {
    int add = (tid >= off) ? sh[tid - off] : 0;
    __syncthreads();
    sh[tid] += add;
    __syncthreads();
  }
  if (i < NN) rs[i] = sh[tid] - v;
  if (tid == 255) bsum[blockIdx.x] = sh[255];
}

__global__ __launch_bounds__(512) void k_scan_bsum(const int* __restrict__ bsum,
                                                   int* __restrict__ boff) {
  __shared__ int sh[512];
  int tid = threadIdx.x;
  int v = (tid < NB_SCAN) ? bsum[tid] : 0;
  sh[tid] = v;
  __syncthreads();
  for (int off = 1; off < 512; off <<= 1) {
    int add = (tid >= off) ? sh[tid - off] : 0;
    __syncthreads();
    sh[tid] += add;
    __syncthreads();
  }
  if (tid < NB_SCAN) boff[tid] = sh[tid] - v;
}

__global__ __launch_bounds__(256) void k_scan_fix(int* __restrict__ rs,
                                                  const int* __restrict__ boff,
                                                  const int* __restrict__ deg,
                                                  float* __restrict__ invd,
                                                  int* __restrict__ fill) {
  int i = blockIdx.x * 256 + threadIdx.x;
  if (i < NN) {
    rs[i] += boff[i >> 8];
    int d = deg[i];
    invd[i] = (d > 0) ? 1.0f / (float)d : 0.0f;
    fill[i] = 0;
  }
  if (i == 0) rs[NN] = EE;
}

__global__ __launch_bounds__(256) void k_fill(const int* __restrict__ ei,
                                              const int* __restrict__ rs,
                                              int* __restrict__ fill,
                                              int* __restrict__ esrc) {
  int e = blockIdx.x * 256 + threadIdx.x;
  if (e >= EE) return;
  unsigned s = (unsigned)ei[e];
  unsigned d = (unsigned)ei[EE + e];
  if (s >= NN) s = 0;
  if (d >= NN) d = 0;
  int p = atomicAdd(&fill[d], 1);
  esrc[rs[d] + p] = (int)s;
}

// ---------------- Dropout mask precompute (bit-exact JAX, partitionable RNG) ----------------
__global__ __launch_bounds__(256) void k_masks(unsigned* __restrict__ masks,
                                               unsigned a0, unsigned a1,
                                               unsigned b0, unsigned b1,
                                               unsigned c0, unsigned c1) {
  unsigned t = blockIdx.x * 256 + threadIdx.x;
  if (t >= 3u * WPL) return;
  unsigned l = t / WPL;
  unsigned w = t - l * WPL;
  unsigned k0 = (l == 0) ? a0 : ((l == 1) ? b0 : c0);
  unsigned k1 = (l == 0) ? a1 : ((l == 1) ? b1 : c1);
  unsigned bits = 0u;
#pragma unroll 4
  for (int b = 0; b < 32; ++b) {
    unsigned i = w * 32u + (unsigned)b;
    unsigned r0, r1;
    tf2x32(k0, k1, 0u, i, r0, r1);
    bits |= ((~(r0 ^ r1)) >> 31) << b;
  }
  masks[t] = bits;
}

// ---------------- Casts ----------------
__global__ __launch_bounds__(256) void k_cast_x(const float* __restrict__ x,
                                                unsigned short* __restrict__ xb) {
  int t = blockIdx.x * 256 + threadIdx.x;
  if (t >= NN * 16) return;  // 8 elems per thread
  const float4* p = (const float4*)x + (size_t)t * 2;
  float4 v0 = p[0], v1 = p[1];
  u16x8 r;
  r[0] = f2bf(v0.x); r[1] = f2bf(v0.y); r[2] = f2bf(v0.z); r[3] = f2bf(v0.w);
  r[4] = f2bf(v1.x); r[5] = f2bf(v1.y); r[6] = f2bf(v1.z); r[7] = f2bf(v1.w);
  *((u16x8*)xb + t) = r;
}

// Wb[l][n][k(256)] = k<128 ? Wl[l][n][k] : Wr[l][n][k-128]; Wob[n][k] = Wo
__global__ __launch_bounds__(256) void k_cast_w(const float* __restrict__ Wl,
                                                const float* __restrict__ Wr,
                                                const float* __restrict__ Wo,
                                                unsigned short* __restrict__ Wb,
                                                unsigned short* __restrict__ Wob) {
  int t = blockIdx.x * 256 + threadIdx.x;
  if (t < 3 * 128 * 256) {
    int l = t >> 15;
    int rem = t & 32767;
    int n = rem >> 8;
    int k = rem & 255;
    float v = (k < 128) ? Wl[(l << 14) + (n << 7) + k] : Wr[(l << 14) + (n << 7) + (k - 128)];
    Wb[t] = f2bf(v);
  } else {
    int t2 = t - 3 * 128 * 256;
    if (t2 < OD * 128) Wob[t2] = f2bf(Wo[t2]);
  }
}

// ---------------- Mean aggregation (bf16 gather, fp32 accum, 4 edges in flight) ----------------
__global__ __launch_bounds__(256) void k_aggb(const unsigned short* __restrict__ xb,
                                              const int* __restrict__ esrc,
                                              const int* __restrict__ rs,
                                              const float* __restrict__ invd,
                                              unsigned short* __restrict__ aggb) {
  int wid = (blockIdx.x * 256 + threadIdx.x) >> 6;  // wave per node
  int lane = threadIdx.x & 63;
  if (wid >= NN) return;
  int s = rs[wid], e = rs[wid + 1];
  int deg = e - s;
  int half = lane >> 5;   // which edge parity this half-wave handles
  int sl = lane & 31;     // ushort4 slice of the 128-col row
  int idx = (s + lane < e) ? esrc[s + lane] : 0;  // one coalesced index load per wave
  const ushort4* xb4 = (const ushort4*)xb;        // row = 32 x ushort4
  float4 accA = {0, 0, 0, 0}, accB = {0, 0, 0, 0};
  int dcap = (deg <= 64) ? deg : 64;
  for (int i0 = half; i0 < dcap; i0 += 4) {
    int iB = i0 + 2;
    int sA = __shfl(idx, i0);
    int sB = __shfl(idx, iB & 63);
    ushort4 vA = xb4[(size_t)sA * 32 + sl];
    float4 fB = {0, 0, 0, 0};
    if (iB < dcap) {
      ushort4 vB = xb4[(size_t)sB * 32 + sl];
      fB.x = bf2f(vB.x); fB.y = bf2f(vB.y); fB.z = bf2f(vB.z); fB.w = bf2f(vB.w);
    }
    accA.x += bf2f(vA.x); accA.y += bf2f(vA.y); accA.z += bf2f(vA.z); accA.w += bf2f(vA.w);
    accB.x += fB.x; accB.y += fB.y; accB.z += fB.z; accB.w += fB.w;
  }
  // ultra-rare deg > 64 tail (uniform-address loads)
  for (int i = 64 + half; i < deg; i += 2) {
    int sX = esrc[s + i];
    ushort4 v = xb4[(size_t)sX * 32 + sl];
    accA.x += bf2f(v.x); accA.y += bf2f(v.y); accA.z += bf2f(v.z); accA.w += bf2f(v.w);
  }
  float4 t;
  t.x = accA.x + accB.x; t.y = accA.y + accB.y;
  t.z = accA.z + accB.z; t.w = accA.w + accB.w;
  t.x += __shfl_xor(t.x, 32); t.y += __shfl_xor(t.y, 32);
  t.z += __shfl_xor(t.z, 32); t.w += __shfl_xor(t.w, 32);
  float sc = invd[wid];
  if (half == 0) {
    ushort4 o;
    o.x = f2bf(t.x * sc); o.y = f2bf(t.y * sc);
    o.z = f2bf(t.z * sc); o.w = f2bf(t.w * sc);
    ((ushort4*)aggb)[(size_t)wid * 32 + sl] = o;
  }
}

// ---------------- Layer: LDS-free bf16 MFMA GEMM + bias/leakyrelu/dropout ----------------
// C[N][128] = [aggb | xin] (K=256) @ Wb^T ; per block 128 rows, wave owns 32.
__global__ __launch_bounds__(256) void k_layer_mfma(
    const unsigned short* __restrict__ xin,   // [NN][128] bf16
    const unsigned short* __restrict__ aggb,  // [NN][128] bf16
    const unsigned short* __restrict__ Wb,    // [128][256] bf16 (this layer)
    const float* __restrict__ bias,           // [128] fp32
    const unsigned* __restrict__ mask,        // this layer's dropout bits
    unsigned short* __restrict__ xout) {
  const int lane = threadIdx.x & 63;
  const int wv = threadIdx.x >> 6;            // 0..3
  const int rbase = blockIdx.x * 128 + wv * 32;
  const int lr = lane & 15;                   // A row / B col within frag
  const int lk = (lane >> 4) * 8;             // k offset within frag

  f32x4 acc[2][8];
#pragma unroll
  for (int i = 0; i < 2; ++i)
#pragma unroll
    for (int j = 0; j < 8; ++j) acc[i][j] = (f32x4){0.f, 0.f, 0.f, 0.f};

  int r0 = rbase + lr;      if (r0 >= NN) r0 = NN - 1;
  int r1 = rbase + 16 + lr; if (r1 >= NN) r1 = NN - 1;

#pragma unroll
  for (int kf = 0; kf < 8; ++kf) {
    const unsigned short* A = (kf < 4) ? aggb : xin;
    const int kc = (kf & 3) * 32 + lk;
    s16x8 a0 = *(const s16x8*)(A + (size_t)r0 * 128 + kc);
    s16x8 a1 = *(const s16x8*)(A + (size_t)r1 * 128 + kc);
    const int wk = kf * 32 + lk;
#pragma unroll
    for (int nf = 0; nf < 8; ++nf) {
      s16x8 b = *(const s16x8*)(Wb + (nf * 16 + lr) * 256 + wk);
      acc[0][nf] = __builtin_amdgcn_mfma_f32_16x16x32_bf16(a0, b, acc[0][nf], 0, 0, 0);
      acc[1][nf] = __builtin_amdgcn_mfma_f32_16x16x32_bf16(a1, b, acc[1][nf], 0, 0, 0);
    }
  }

  const int rowg = (lane >> 4) * 4;
#pragma unroll
  for (int nf = 0; nf < 8; ++nf) {
    const int col = nf * 16 + lr;
    const float bv = bias[col];
#pragma unroll
    for (int mf = 0; mf < 2; ++mf) {
#pragma unroll
      for (int r = 0; r < 4; ++r) {
        int row = rbase + mf * 16 + rowg + r;
        if (row < NN) {
          float v = acc[mf][nf][r] + bv;
          v = (v > 0.0f) ? v : 0.01f * v;
          unsigned flat = (unsigned)row * 128u + (unsigned)col;
          unsigned mw = mask[flat >> 5];
          v = ((mw >> (flat & 31u)) & 1u) ? (v + v) : 0.0f;
          xout[(size_t)row * 128 + col] = f2bf(v);
        }
      }
    }
  }
}

// ---------------- Final projection: out(fp32)[N][64] = xin @ Wob^T + bo ----------------
__global__ __launch_bounds__(256) void k_final_mfma(
    const unsigned short* __restrict__ xin,  // [NN][128] bf16
    const unsigned short* __restrict__ Wob,  // [64][128] bf16
    const float* __restrict__ bo,            // [64]
    float* __restrict__ out) {
  const int lane = threadIdx.x & 63;
  const int wv = threadIdx.x >> 6;
  const int rbase = blockIdx.x * 128 + wv * 32;
  const int lr = lane & 15;
  const int lk = (lane >> 4) * 8;

  f32x4 acc[2][4];
#pragma unroll
  for (int i = 0; i < 2; ++i)
#pragma unroll
    for (int j = 0; j < 4; ++j) acc[i][j] = (f32x4){0.f, 0.f, 0.f, 0.f};

  int r0 = rbase + lr;      if (r0 >= NN) r0 = NN - 1;
  int r1 = rbase + 16 + lr; if (r1 >= NN) r1 = NN - 1;

#pragma unroll
  for (int kf = 0; kf < 4; ++kf) {
    const int kc = kf * 32 + lk;
    s16x8 a0 = *(const s16x8*)(xin + (size_t)r0 * 128 + kc);
    s16x8 a1 = *(const s16x8*)(xin + (size_t)r1 * 128 + kc);
#pragma unroll
    for (int nf = 0; nf < 4; ++nf) {
      s16x8 b = *(const s16x8*)(Wob + (nf * 16 + lr) * 128 + kc);
      acc[0][nf] = __builtin_amdgcn_mfma_f32_16x16x32_bf16(a0, b, acc[0][nf], 0, 0, 0);
      acc[1][nf] = __builtin_amdgcn_mfma_f32_16x16x32_bf16(a1, b, acc[1][nf], 0, 0, 0);
    }
  }

  const int rowg = (lane >> 4) * 4;
#pragma unroll
  for (int nf = 0; nf < 4; ++nf) {
    const int col = nf * 16 + lr;
    const float bv = bo[col];
#pragma unroll
    for (int mf = 0; mf < 2; ++mf) {
#pragma unroll
      for (int r = 0; r < 4; ++r) {
        int row = rbase + mf * 16 + rowg + r;
        if (row < NN) out[(size_t)row * 64 + col] = acc[mf][nf][r] + bv;
      }
    }
  }
}

// ---------------- Host launch ----------------
extern "C" void kernel_launch(void* const* d_in, const int* in_sizes, int n_in,
                              void* d_out, int out_size, void* d_ws, size_t ws_size,
                              hipStream_t stream) {
  const float* x  = (const float*)d_in[0];
  const int*   ei = (const int*)d_in[1];
  const float* Wl = (const float*)d_in[2];
  const float* Wr = (const float*)d_in[3];
  const float* b  = (const float*)d_in[4];
  const float* Wo = (const float*)d_in[5];
  const float* bo = (const float*)d_in[6];
  float* out = (float*)d_out;

  char* wsp = (char*)d_ws;
  size_t off = 0;
  auto take = [&](size_t bytes) -> void* {
    off = (off + 255) & ~(size_t)255;
    void* p = wsp + off;
    off += bytes;
    return p;
  };
  unsigned short* xb0  = (unsigned short*)take((size_t)NN * 128 * 2);
  unsigned short* act1 = (unsigned short*)take((size_t)NN * 128 * 2);
  unsigned short* act2 = (unsigned short*)take((size_t)NN * 128 * 2);
  unsigned short* aggb = (unsigned short*)take((size_t)NN * 128 * 2);
  unsigned short* Wb   = (unsigned short*)take((size_t)3 * 128 * 256 * 2);
  unsigned short* Wob  = (unsigned short*)take((size_t)OD * 128 * 2);
  unsigned* masks = (unsigned*)take((size_t)3 * WPL * 4);
  int*   rs   = (int*)take((size_t)(NN + 1) * 4);
  int*   esrc = (int*)take((size_t)EE * 4);
  int*   deg  = (int*)take((size_t)NN * 4);
  int*   fill = (int*)take((size_t)NN * 4);
  float* invd = (float*)take((size_t)NN * 4);
  int*   bsum = (int*)take(512 * 4);
  int*   boff = (int*)take(512 * 4);

  // ---- CSR build ----
  hipMemsetAsync(deg, 0, (size_t)NN * 4, stream);
  k_deg<<<(EE + 255) / 256, 256, 0, stream>>>(ei, deg);
  k_scan_block<<<NB_SCAN, 256, 0, stream>>>(deg, rs, bsum);
  k_scan_bsum<<<1, 512, 0, stream>>>(bsum, boff);
  k_scan_fix<<<NB_SCAN, 256, 0, stream>>>(rs, boff, deg, invd, fill);
  k_fill<<<(EE + 255) / 256, 256, 0, stream>>>(ei, rs, fill, esrc);

  // ---- dropout masks ----
  unsigned fk[3][2];
  for (int l = 0; l < 3; ++l) tf2x32(0u, 42u, 0u, (unsigned)l, fk[l][0], fk[l][1]);
  k_masks<<<(3 * WPL + 255) / 256, 256, 0, stream>>>(masks, fk[0][0], fk[0][1],
                                                     fk[1][0], fk[1][1], fk[2][0], fk[2][1]);

  // ---- casts ----
  k_cast_x<<<(NN * 16 + 255) / 256, 256, 0, stream>>>(x, xb0);
  k_cast_w<<<(3 * 128 * 256 + OD * 128 + 255) / 256, 256, 0, stream>>>(Wl, Wr, Wo, Wb, Wob);

  // ---- layers ----
  const int gemmBlocks = (NN + 127) / 128;  // 782
  const int aggBlocks  = (NN + 3) / 4;      // 25000 (wave per node)

  k_aggb<<<aggBlocks, 256, 0, stream>>>(xb0, esrc, rs, invd, aggb);
  k_layer_mfma<<<gemmBlocks, 256, 0, stream>>>(xb0, aggb, Wb, b, masks, act1);

  k_aggb<<<aggBlocks, 256, 0, stream>>>(act1, esrc, rs, invd, aggb);
  k_layer_mfma<<<gemmBlocks, 256, 0, stream>>>(act1, aggb, Wb + 32768, b + 128,
                                               masks + WPL, act2);

  k_aggb<<<aggBlocks, 256, 0, stream>>>(act2, esrc, rs, invd, aggb);
  k_layer_mfma<<<gemmBlocks, 256, 0, stream>>>(act2, aggb, Wb + 65536, b + 256,
                                               masks + 2 * WPL, act1);

  k_final_mfma<<<gemmBlocks, 256, 0, stream>>>(act1, Wob, bo, out);

  (void)in_sizes; (void)n_in; (void)out_size; (void)ws_size;
}

// Round 3
// 417.307 us; speedup vs baseline: 1.7926x; 1.2448x over previous
//
#include <hip/hip_runtime.h>
#include <cstdint>
#include <cstddef>

// Problem constants (fixed by reference)
#define NN 100000          // nodes
#define EE 800000          // edges
#define HD 128             // hidden dim
#define OD 64              // output dim
#define NB_SCAN 391        // ceil(NN/256)
#define WPL 400000         // dropout mask words per layer = NN*HD/32

typedef __attribute__((ext_vector_type(8))) short s16x8;
typedef __attribute__((ext_vector_type(4))) float f32x4;
typedef __attribute__((ext_vector_type(8))) unsigned short u16x8;

// RNE float -> bf16
__device__ __forceinline__ unsigned short f2bf(float f) {
  unsigned u = __float_as_uint(f);
  return (unsigned short)((u + 0x7FFFu + ((u >> 16) & 1u)) >> 16);
}
__device__ __forceinline__ float bf2f(unsigned short v) {
  return __uint_as_float(((unsigned)v) << 16);
}

__host__ __device__ __forceinline__ unsigned rotl32(unsigned x, int r) {
#ifdef __HIP_DEVICE_COMPILE__
  return __builtin_amdgcn_alignbit(x, x, 32 - r);  // (x<<r)|(x>>(32-r)), 1 instr
#else
  return (x << r) | (x >> (32 - r));
#endif
}

// ---------------- Threefry-2x32 (20 rounds), bit-exact vs JAX ----------------
__host__ __device__ __forceinline__ void tf2x32(unsigned k0, unsigned k1,
                                                unsigned x0, unsigned x1,
                                                unsigned& o0, unsigned& o1) {
  unsigned ks2 = k0 ^ k1 ^ 0x1BD11BDAu;
#define TFR(r) { x0 += x1; x1 = rotl32(x1, (r)) ^ x0; }
  x0 += k0; x1 += k1;
  TFR(13) TFR(15) TFR(26) TFR(6)
  x0 += k1; x1 += ks2 + 1u;
  TFR(17) TFR(29) TFR(16) TFR(24)
  x0 += ks2; x1 += k0 + 2u;
  TFR(13) TFR(15) TFR(26) TFR(6)
  x0 += k0; x1 += k1 + 3u;
  TFR(17) TFR(29) TFR(16) TFR(24)
  x0 += k1; x1 += ks2 + 4u;
  TFR(13) TFR(15) TFR(26) TFR(6)
  x0 += ks2; x1 += k0 + 5u;
#undef TFR
  o0 = x0; o1 = x1;
}

// ---------------- CSR build ----------------
__global__ __launch_bounds__(256) void k_deg(const int* __restrict__ ei,
                                             int* __restrict__ deg) {
  int e = blockIdx.x * 256 + threadIdx.x;
  if (e >= EE) return;
  unsigned d = (unsigned)ei[EE + e];
  if (d >= NN) d = 0;
  atomicAdd(&deg[d], 1);
}

__global__ __launch_bounds__(256) void k_scan_block(const int* __restrict__ deg,
                                                    int* __restrict__ rs,
                                                    int* __restrict__ bsum) {
  __shared__ int sh[256];
  int tid = threadIdx.x;
  int i = blockIdx.x * 256 + tid;
  int v = (i < NN) ? deg[i] : 0;
  sh[tid] = v;
  __syncthreads();
  for (int off = 1; off < 256; off <<= 1) {
    int add = (tid >= off) ? sh[tid - off] : 0;
    __syncthreads();
    sh[tid] += add;
    __syncthreads();
  }
  if (i < NN) rs[i] = sh[tid] - v;
  if (tid == 255) bsum[blockIdx.x] = sh[255];
}

__global__ __launch_bounds__(512) void k_scan_bsum(const int* __restrict__ bsum,
                                                   int* __restrict__ boff) {
  __shared__ int sh[512];
  int tid = threadIdx.x;
  int v = (tid < NB_SCAN) ? bsum[tid] : 0;
  sh[tid] = v;
  __syncthreads();
  for (int off = 1; off < 512; off <<= 1) {
    int add = (tid >= off) ? sh[tid - off] : 0;
    __syncthreads();
    sh[tid] += add;
    __syncthreads();
  }
  if (tid < NB_SCAN) boff[tid] = sh[tid] - v;
}

__global__ __launch_bounds__(256) void k_scan_fix(int* __restrict__ rs,
                                                  const int* __restrict__ boff,
                                                  const int* __restrict__ deg,
                                                  float* __restrict__ invd,
                                                  int* __restrict__ fill) {
  int i = blockIdx.x * 256 + threadIdx.x;
  if (i < NN) {
    rs[i] += boff[i >> 8];
    int d = deg[i];
    invd[i] = (d > 0) ? 1.0f / (float)d : 0.0f;
    fill[i] = 0;
  }
  if (i == 0) rs[NN] = EE;
}

__global__ __launch_bounds__(256) void k_fill(const int* __restrict__ ei,
                                              const int* __restrict__ rs,
                                              int* __restrict__ fill,
                                              int* __restrict__ esrc) {
  int e = blockIdx.x * 256 + threadIdx.x;
  if (e >= EE) return;
  unsigned s = (unsigned)ei[e];
  unsigned d = (unsigned)ei[EE + e];
  if (s >= NN) s = 0;
  if (d >= NN) d = 0;
  int p = atomicAdd(&fill[d], 1);
  esrc[rs[d] + p] = (int)s;
}

// ---------------- Fused casts (x -> bf16, [Wl|Wr] -> Wb, Wo -> Wob) ----------------
__global__ __launch_bounds__(256) void k_cast(const float* __restrict__ x,
                                              const float* __restrict__ Wl,
                                              const float* __restrict__ Wr,
                                              const float* __restrict__ Wo,
                                              unsigned short* __restrict__ xb,
                                              unsigned short* __restrict__ Wb,
                                              unsigned short* __restrict__ Wob) {
  int t = blockIdx.x * 256 + threadIdx.x;
  if (t < NN * 16) {  // 8 elems per thread
    const float4* p = (const float4*)x + (size_t)t * 2;
    float4 v0 = p[0], v1 = p[1];
    u16x8 r;
    r[0] = f2bf(v0.x); r[1] = f2bf(v0.y); r[2] = f2bf(v0.z); r[3] = f2bf(v0.w);
    r[4] = f2bf(v1.x); r[5] = f2bf(v1.y); r[6] = f2bf(v1.z); r[7] = f2bf(v1.w);
    *((u16x8*)xb + t) = r;
  } else {
    int t2 = t - NN * 16;
    if (t2 < 3 * 128 * 256) {
      int l = t2 >> 15;
      int rem = t2 & 32767;
      int n = rem >> 8;
      int k = rem & 255;
      float v = (k < 128) ? Wl[(l << 14) + (n << 7) + k] : Wr[(l << 14) + (n << 7) + (k - 128)];
      Wb[t2] = f2bf(v);
    } else {
      int t3 = t2 - 3 * 128 * 256;
      if (t3 < OD * 128) Wob[t3] = f2bf(Wo[t3]);
    }
  }
}

// ---------------- Mean aggregation + fused dropout-mask gen ----------------
// 1 node per half-wave, 4 gather streams in flight; exact-fit grid (no early exit,
// ballot needs all 64 lanes). Threefry work hides under gather latency.
__global__ __launch_bounds__(256) void k_aggb(const unsigned short* __restrict__ xb,
                                              const int* __restrict__ esrc,
                                              const int* __restrict__ rs,
                                              const float* __restrict__ invd,
                                              unsigned short* __restrict__ aggb,
                                              unsigned* __restrict__ maskL,
                                              unsigned mk0, unsigned mk1) {
  const int w = (blockIdx.x * 256 + threadIdx.x) >> 6;  // wave 0..49999
  const int lane = threadIdx.x & 63;
  const int h = lane >> 5;
  const int sl = lane & 31;
  const int hb = h << 5;
  const int n = (w << 1) + h;  // node, < 100000 always

  // issue CSR loads early (overlap with threefry below)
  const int s = rs[n];
  const int e = rs[n + 1];
  const int deg = e - s;
  int idx = (sl < deg) ? esrc[s + sl] : 0;
  const float sc = invd[n];

  // fused dropout-mask generation: wave w covers elements [w*256, w*256+256)
  {
    const unsigned ebase = (unsigned)w * 256u + (unsigned)lane;
#pragma unroll
    for (int c = 0; c < 4; ++c) {
      unsigned r0, r1;
      tf2x32(mk0, mk1, 0u, ebase + (unsigned)(c << 6), r0, r1);
      unsigned long long m = __ballot(((r0 ^ r1) & 0x80000000u) == 0u);
      if (lane == 0) ((unsigned long long*)maskL)[(w << 2) + c] = m;
    }
  }

  const ushort4* xb4 = (const ushort4*)xb;
  float4 a0 = {0, 0, 0, 0}, a1 = a0, a2 = a0, a3 = a0;
  const int dcap = (deg < 32) ? deg : 32;
  int i0 = 0;
  for (; i0 + 4 <= dcap; i0 += 4) {  // 4 gathers in flight per half-wave
    int j0 = __shfl(idx, hb + i0);
    int j1 = __shfl(idx, hb + i0 + 1);
    int j2 = __shfl(idx, hb + i0 + 2);
    int j3 = __shfl(idx, hb + i0 + 3);
    ushort4 v0 = xb4[(size_t)j0 * 32 + sl];
    ushort4 v1 = xb4[(size_t)j1 * 32 + sl];
    ushort4 v2 = xb4[(size_t)j2 * 32 + sl];
    ushort4 v3 = xb4[(size_t)j3 * 32 + sl];
    a0.x += bf2f(v0.x); a0.y += bf2f(v0.y); a0.z += bf2f(v0.z); a0.w += bf2f(v0.w);
    a1.x += bf2f(v1.x); a1.y += bf2f(v1.y); a1.z += bf2f(v1.z); a1.w += bf2f(v1.w);
    a2.x += bf2f(v2.x); a2.y += bf2f(v2.y); a2.z += bf2f(v2.z); a2.w += bf2f(v2.w);
    a3.x += bf2f(v3.x); a3.y += bf2f(v3.y); a3.z += bf2f(v3.z); a3.w += bf2f(v3.w);
  }
  if (i0 < dcap) {
    int j = __shfl(idx, hb + i0);
    ushort4 v = xb4[(size_t)j * 32 + sl];
    a0.x += bf2f(v.x); a0.y += bf2f(v.y); a0.z += bf2f(v.z); a0.w += bf2f(v.w);
  }
  if (i0 + 1 < dcap) {
    int j = __shfl(idx, hb + i0 + 1);
    ushort4 v = xb4[(size_t)j * 32 + sl];
    a1.x += bf2f(v.x); a1.y += bf2f(v.y); a1.z += bf2f(v.z); a1.w += bf2f(v.w);
  }
  if (i0 + 2 < dcap) {
    int j = __shfl(idx, hb + i0 + 2);
    ushort4 v = xb4[(size_t)j * 32 + sl];
    a2.x += bf2f(v.x); a2.y += bf2f(v.y); a2.z += bf2f(v.z); a2.w += bf2f(v.w);
  }
  // rare deg > 32 tail (uniform address per half-wave)
  for (int i = 32; i < deg; ++i) {
    int sX = esrc[s + i];
    ushort4 v = xb4[(size_t)sX * 32 + sl];
    a3.x += bf2f(v.x); a3.y += bf2f(v.y); a3.z += bf2f(v.z); a3.w += bf2f(v.w);
  }

  float4 t;
  t.x = (a0.x + a1.x) + (a2.x + a3.x);
  t.y = (a0.y + a1.y) + (a2.y + a3.y);
  t.z = (a0.z + a1.z) + (a2.z + a3.z);
  t.w = (a0.w + a1.w) + (a2.w + a3.w);
  ushort4 o;
  o.x = f2bf(t.x * sc); o.y = f2bf(t.y * sc);
  o.z = f2bf(t.z * sc); o.w = f2bf(t.w * sc);
  ((ushort4*)aggb)[(size_t)n * 32 + sl] = o;
}

// ---------------- Layer: LDS-free bf16 MFMA GEMM (operands swapped) ----------------
// D = mfma(W_frag, Act_frag): col(lane&15)=node, row-part=out-col -> each thread
// holds 4 consecutive out-cols of one node -> ushort4 stores.
__global__ __launch_bounds__(256) void k_layer_mfma(
    const unsigned short* __restrict__ xin,   // [NN][128] bf16
    const unsigned short* __restrict__ aggb,  // [NN][128] bf16
    const unsigned short* __restrict__ Wb,    // [128][256] bf16 (this layer)
    const float* __restrict__ bias,           // [128] fp32
    const unsigned* __restrict__ mask,        // this layer's dropout bits
    unsigned short* __restrict__ xout) {
  const int lane = threadIdx.x & 63;
  const int wv = threadIdx.x >> 6;
  const int rbase = blockIdx.x * 128 + wv * 32;
  const int lr = lane & 15;
  const int lk = (lane >> 4) * 8;
  const int rowg = (lane >> 4) * 4;

  f32x4 acc[2][8];
#pragma unroll
  for (int i = 0; i < 2; ++i)
#pragma unroll
    for (int j = 0; j < 8; ++j) acc[i][j] = (f32x4){0.f, 0.f, 0.f, 0.f};

  int n0 = rbase + lr;      if (n0 >= NN) n0 = NN - 1;
  int n1 = rbase + 16 + lr; if (n1 >= NN) n1 = NN - 1;

#pragma unroll
  for (int kf = 0; kf < 8; ++kf) {
    const unsigned short* A = (kf < 4) ? aggb : xin;
    const int kc = (kf & 3) * 32 + lk;
    s16x8 act0 = *(const s16x8*)(A + (size_t)n0 * 128 + kc);
    s16x8 act1 = *(const s16x8*)(A + (size_t)n1 * 128 + kc);
    const int wk = kf * 32 + lk;
#pragma unroll
    for (int nf = 0; nf < 8; ++nf) {
      s16x8 wfr = *(const s16x8*)(Wb + (nf * 16 + lr) * 256 + wk);
      acc[0][nf] = __builtin_amdgcn_mfma_f32_16x16x32_bf16(wfr, act0, acc[0][nf], 0, 0, 0);
      acc[1][nf] = __builtin_amdgcn_mfma_f32_16x16x32_bf16(wfr, act1, acc[1][nf], 0, 0, 0);
    }
  }

#pragma unroll
  for (int mf = 0; mf < 2; ++mf) {
    const int node = rbase + mf * 16 + lr;
    if (node >= NN) continue;
    const unsigned mbase = (unsigned)node * 4u;
#pragma unroll
    for (int nf = 0; nf < 8; ++nf) {
      const int colb = nf * 16 + rowg;
      const float4 bv = *(const float4*)(bias + colb);
      const unsigned mw = mask[mbase + (colb >> 5)];
      const unsigned sh = (unsigned)(colb & 31);
      float v0 = acc[mf][nf][0] + bv.x;
      float v1 = acc[mf][nf][1] + bv.y;
      float v2 = acc[mf][nf][2] + bv.z;
      float v3 = acc[mf][nf][3] + bv.w;
      v0 = (v0 > 0.f) ? v0 : 0.01f * v0;
      v1 = (v1 > 0.f) ? v1 : 0.01f * v1;
      v2 = (v2 > 0.f) ? v2 : 0.01f * v2;
      v3 = (v3 > 0.f) ? v3 : 0.01f * v3;
      ushort4 o;
      o.x = ((mw >> (sh + 0)) & 1u) ? f2bf(v0 + v0) : (unsigned short)0;
      o.y = ((mw >> (sh + 1)) & 1u) ? f2bf(v1 + v1) : (unsigned short)0;
      o.z = ((mw >> (sh + 2)) & 1u) ? f2bf(v2 + v2) : (unsigned short)0;
      o.w = ((mw >> (sh + 3)) & 1u) ? f2bf(v3 + v3) : (unsigned short)0;
      *(ushort4*)(xout + (size_t)node * 128 + colb) = o;
    }
  }
}

// ---------------- Final projection: out(fp32)[N][64] = xin @ Wob^T + bo ----------------
__global__ __launch_bounds__(256) void k_final_mfma(
    const unsigned short* __restrict__ xin,  // [NN][128] bf16
    const unsigned short* __restrict__ Wob,  // [64][128] bf16
    const float* __restrict__ bo,            // [64]
    float* __restrict__ out) {
  const int lane = threadIdx.x & 63;
  const int wv = threadIdx.x >> 6;
  const int rbase = blockIdx.x * 128 + wv * 32;
  const int lr = lane & 15;
  const int lk = (lane >> 4) * 8;
  const int rowg = (lane >> 4) * 4;

  f32x4 acc[2][4];
#pragma unroll
  for (int i = 0; i < 2; ++i)
#pragma unroll
    for (int j = 0; j < 4; ++j) acc[i][j] = (f32x4){0.f, 0.f, 0.f, 0.f};

  int n0 = rbase + lr;      if (n0 >= NN) n0 = NN - 1;
  int n1 = rbase + 16 + lr; if (n1 >= NN) n1 = NN - 1;

#pragma unroll
  for (int kf = 0; kf < 4; ++kf) {
    const int kc = kf * 32 + lk;
    s16x8 act0 = *(const s16x8*)(xin + (size_t)n0 * 128 + kc);
    s16x8 act1 = *(const s16x8*)(xin + (size_t)n1 * 128 + kc);
#pragma unroll
    for (int nf = 0; nf < 4; ++nf) {
      s16x8 wfr = *(const s16x8*)(Wob + (nf * 16 + lr) * 128 + kc);
      acc[0][nf] = __builtin_amdgcn_mfma_f32_16x16x32_bf16(wfr, act0, acc[0][nf], 0, 0, 0);
      acc[1][nf] = __builtin_amdgcn_mfma_f32_16x16x32_bf16(wfr, act1, acc[1][nf], 0, 0, 0);
    }
  }

#pragma unroll
  for (int mf = 0; mf < 2; ++mf) {
    const int node = rbase + mf * 16 + lr;
    if (node >= NN) continue;
#pragma unroll
    for (int nf = 0; nf < 4; ++nf) {
      const int colb = nf * 16 + rowg;
      const float4 bv = *(const float4*)(bo + colb);
      float4 o;
      o.x = acc[mf][nf][0] + bv.x;
      o.y = acc[mf][nf][1] + bv.y;
      o.z = acc[mf][nf][2] + bv.z;
      o.w = acc[mf][nf][3] + bv.w;
      *(float4*)(out + (size_t)node * 64 + colb) = o;
    }
  }
}

// ---------------- Host launch ----------------
extern "C" void kernel_launch(void* const* d_in, const int* in_sizes, int n_in,
                              void* d_out, int out_size, void* d_ws, size_t ws_size,
                              hipStream_t stream) {
  const float* x  = (const float*)d_in[0];
  const int*   ei = (const int*)d_in[1];
  const float* Wl = (const float*)d_in[2];
  const float* Wr = (const float*)d_in[3];
  const float* b  = (const float*)d_in[4];
  const float* Wo = (const float*)d_in[5];
  const float* bo = (const float*)d_in[6];
  float* out = (float*)d_out;

  char* wsp = (char*)d_ws;
  size_t off = 0;
  auto take = [&](size_t bytes) -> void* {
    off = (off + 255) & ~(size_t)255;
    void* p = wsp + off;
    off += bytes;
    return p;
  };
  unsigned short* xb0  = (unsigned short*)take((size_t)NN * 128 * 2);
  unsigned short* act1 = (unsigned short*)take((size_t)NN * 128 * 2);
  unsigned short* act2 = (unsigned short*)take((size_t)NN * 128 * 2);
  unsigned short* aggb = (unsigned short*)take((size_t)NN * 128 * 2);
  unsigned short* Wb   = (unsigned short*)take((size_t)3 * 128 * 256 * 2);
  unsigned short* Wob  = (unsigned short*)take((size_t)OD * 128 * 2);
  unsigned* masks = (unsigned*)take((size_t)3 * WPL * 4);
  int*   rs   = (int*)take((size_t)(NN + 1) * 4);
  int*   esrc = (int*)take((size_t)EE * 4);
  int*   deg  = (int*)take((size_t)NN * 4);
  int*   fill = (int*)take((size_t)NN * 4);
  float* invd = (float*)take((size_t)NN * 4);
  int*   bsum = (int*)take(512 * 4);
  int*   boff = (int*)take(512 * 4);

  // ---- CSR build ----
  hipMemsetAsync(deg, 0, (size_t)NN * 4, stream);
  k_deg<<<(EE + 255) / 256, 256, 0, stream>>>(ei, deg);
  k_scan_block<<<NB_SCAN, 256, 0, stream>>>(deg, rs, bsum);
  k_scan_bsum<<<1, 512, 0, stream>>>(bsum, boff);
  k_scan_fix<<<NB_SCAN, 256, 0, stream>>>(rs, boff, deg, invd, fill);
  k_fill<<<(EE + 255) / 256, 256, 0, stream>>>(ei, rs, fill, esrc);

  // ---- casts (x, weights) ----
  k_cast<<<6666, 256, 0, stream>>>(x, Wl, Wr, Wo, xb0, Wb, Wob);

  // ---- per-layer fold_in keys (host-side threefry: key(42) fold l) ----
  unsigned fk[3][2];
  for (int l = 0; l < 3; ++l) tf2x32(0u, 42u, 0u, (unsigned)l, fk[l][0], fk[l][1]);

  // ---- layers (mask for layer l generated inside k_aggb of layer l) ----
  const int gemmBlocks = (NN + 127) / 128;  // 782
  const int aggBlocks  = 12500;             // 50000 waves, 2 nodes/wave, exact fit

  k_aggb<<<aggBlocks, 256, 0, stream>>>(xb0, esrc, rs, invd, aggb,
                                        masks, fk[0][0], fk[0][1]);
  k_layer_mfma<<<gemmBlocks, 256, 0, stream>>>(xb0, aggb, Wb, b, masks, act1);

  k_aggb<<<aggBlocks, 256, 0, stream>>>(act1, esrc, rs, invd, aggb,
                                        masks + WPL, fk[1][0], fk[1][1]);
  k_layer_mfma<<<gemmBlocks, 256, 0, stream>>>(act1, aggb, Wb + 32768, b + 128,
                                               masks + WPL, act2);

  k_aggb<<<aggBlocks, 256, 0, stream>>>(act2, esrc, rs, invd, aggb,
                                        masks + 2 * WPL, fk[2][0], fk[2][1]);
  k_layer_mfma<<<gemmBlocks, 256, 0, stream>>>(act2, aggb, Wb + 65536, b + 256,
                                               masks + 2 * WPL, act1);

  k_final_mfma<<<gemmBlocks, 256, 0, stream>>>(act1, Wob, bo, out);

  (void)in_sizes; (void)n_in; (void)out_size; (void)ws_size;
}